// Round 10
// baseline (125.900 us; speedup 1.0000x reference)
//
#include <hip/hip_runtime.h>
#include <cstdint>

#define B_ 16
#define S_ 1024
#define D_ 512
#define TILE 128
#define BK 32
#define PITCH 36   // legacy-path LDS pitch

typedef float f32x4 __attribute__((ext_vector_type(4)));
typedef short s16x8 __attribute__((ext_vector_type(8)));
typedef unsigned short u16;
typedef unsigned int u32;

__device__ __forceinline__ u16 f2bf(float f) {
    u32 u = __builtin_bit_cast(u32, f);
    u += 0x7FFFu + ((u >> 16) & 1u);
    return (u16)(u >> 16);
}
__device__ __forceinline__ float bf2f(u16 h) {
    return __builtin_bit_cast(float, (u32)h << 16);
}

#define GLD16(g, l) __builtin_amdgcn_global_load_lds( \
    (const __attribute__((address_space(1))) u32*)(g), \
    (__attribute__((address_space(3))) u32*)(l), 16, 0, 0)

// per-batch compact causal P_t elems: sum_qt (qt+1)*128*128 = 589824
#define PT_BATCH 589824
__device__ __forceinline__ int tri128(int qt) {   // tri(qt)*16384
    return ((qt * (qt + 1)) >> 1) * 16384;
}

// ===== prep2: cvt(K) + transpose-cvt(V) (Q consumed fp32 directly by qk3) =====
#define TP 66
__global__ __launch_bounds__(256) void prep2_kernel(const float* __restrict__ k,
                                                    const float* __restrict__ v,
                                                    u16* __restrict__ Kb,
                                                    u16* __restrict__ Vt) {
    __shared__ u16 t[64 * TP];
    const int bid = blockIdx.x;
    const int tid = threadIdx.x;
    if (bid < 4096) {   // cvt K
        int i = ((bid * 256) + tid) * 8;
        float4 a = *(const float4*)(k + i);
        float4 b2 = *(const float4*)(k + i + 4);
        union { ushort4 h[2]; s16x8 v; } r;
        r.h[0] = make_ushort4(f2bf(a.x), f2bf(a.y), f2bf(a.z), f2bf(a.w));
        r.h[1] = make_ushort4(f2bf(b2.x), f2bf(b2.y), f2bf(b2.z), f2bf(b2.w));
        *(s16x8*)(Kb + i) = r.v;
    } else {            // trv tile
        int tt = bid - 4096;                 // 0..2047
        const int d0 = (tt & 7) * 64, j0 = ((tt >> 3) & 15) * 64, b = tt >> 7;
        const int tj = tid >> 2;
        const int td = (tid & 3) * 16;
        const float* src = v + ((size_t)b * S_ + j0 + tj) * D_ + d0 + td;
#pragma unroll
        for (int e = 0; e < 4; ++e) {
            float4 a = *(const float4*)(src + e * 4);
            *(ushort4*)(t + tj * TP + td + e * 4) =
                make_ushort4(f2bf(a.x), f2bf(a.y), f2bf(a.z), f2bf(a.w));
        }
        __syncthreads();
        const int dd = tid >> 2;
        const int jj = (tid & 3) * 16;
        u16* dstp = Vt + ((size_t)b * D_ + d0 + dd) * S_ + j0 + jj;
        u16 tmp[16];
#pragma unroll
        for (int e = 0; e < 16; ++e) tmp[e] = t[(jj + e) * TP + dd];
        *(s16x8*)dstp = *(s16x8*)tmp;
        *(s16x8*)(dstp + 8) = *(s16x8*)(tmp + 8);
    }
}

// swizzled LDS read: logical [row][col(64 bf16)] stored with byte ^= (row&7)<<4
__device__ __forceinline__ s16x8 frag_swz(const u16* lds, int row, int colbyte) {
    int off = row * 128 + (colbyte ^ ((row & 7) << 4));
    return *(const s16x8*)((const char*)lds + off);
}

// ===== qk3: QK^T (A = Q fp32 reg-staged, B = Kb via GLD16) + exp(v - M_t) -> Pt + stats =====
__global__ __launch_bounds__(256) void qk3_kernel(const float* __restrict__ q,
                                                  const u16* __restrict__ Kb,
                                                  const int* __restrict__ rep,
                                                  u16* __restrict__ Pt,
                                                  float2* __restrict__ st) {
    const int bid = blockIdx.x;
    const int xcd = bid & 7;
    const int w = bid >> 3;            // 0..71
    const int b = xcd * 2 + (w & 1);
    int p = 35 - (w >> 1);             // LPT: large qt first; Q panel hot across kt
    int qt = 0, tri = 0;
    while (p >= tri + qt + 1) { tri += qt + 1; ++qt; }
    const int kt = p - tri;
    const int nkq = (qt + 1) * 128;

    __shared__ u16 lA[128 * 64];
    __shared__ u16 lB[128 * 64];
    __shared__ int lrepr[128];
    __shared__ int lrepc[128];
    __shared__ float lst[2][64][2][2];   // [row half][row64][col half][max/sum]

    const int tid = threadIdx.x, lane = tid & 63, wid = tid >> 6;
    const int l8 = lane >> 3, l7 = lane & 7;
    const int cswz = (l7 ^ l8) * 8;
    const int r15 = lane & 15, g4 = lane >> 4;

    if (tid < 128) lrepr[tid] = rep[(size_t)b * S_ + qt * 128 + tid];
    else lrepc[tid - 128] = rep[(size_t)b * S_ + kt * 128 + (tid - 128)];

    const u16* bg = Kb + ((size_t)b * S_ + (size_t)kt * 128) * D_;
    const u16* gb[4];
#pragma unroll
    for (int q2 = 0; q2 < 4; ++q2)
        gb[q2] = bg + (size_t)((wid * 4 + q2) * 8 + l8) * D_ + cswz;

    const float* ag = q + ((size_t)b * S_ + (size_t)qt * 128) * D_;
    const int au = tid & 7;
    const int ar0 = (tid >> 3) * 4;

    f32x4 acc[4][4] = {};
    const int wr = (wid >> 1) * 64, wc = (wid & 1) * 64;
    const int cb = g4 * 16;

    for (int kk = 0; kk < D_; kk += 64) {
#pragma unroll
        for (int q2 = 0; q2 < 4; ++q2)
            GLD16(gb[q2] + kk, lB + (wid * 4 + q2) * 512);
#pragma unroll
        for (int rr = 0; rr < 4; ++rr) {
            int row = ar0 + rr;
            const float* src = ag + (size_t)row * D_ + kk + au * 8;
            float4 x0 = *(const float4*)src;
            float4 x1 = *(const float4*)(src + 4);
            union { ushort4 h[2]; s16x8 v; } rv;
            rv.h[0] = make_ushort4(f2bf(x0.x), f2bf(x0.y), f2bf(x0.z), f2bf(x0.w));
            rv.h[1] = make_ushort4(f2bf(x1.x), f2bf(x1.y), f2bf(x1.z), f2bf(x1.w));
            *(s16x8*)(lA + row * 64 + (au ^ (row & 7)) * 8) = rv.v;
        }
        __syncthreads();
#pragma unroll
        for (int ks = 0; ks < 2; ++ks) {
            s16x8 af[4], bf4[4];
#pragma unroll
            for (int m = 0; m < 4; ++m) af[m] = frag_swz(lA, wr + m * 16 + r15, ks * 64 + cb);
#pragma unroll
            for (int n = 0; n < 4; ++n) bf4[n] = frag_swz(lB, wc + n * 16 + r15, ks * 64 + cb);
#pragma unroll
            for (int m = 0; m < 4; ++m)
#pragma unroll
                for (int n = 0; n < 4; ++n)
                    acc[m][n] = __builtin_amdgcn_mfma_f32_16x16x32_bf16(af[m], bf4[n], acc[m][n], 0, 0, 0);
        }
        __syncthreads();
    }

    // ---- epilogue pass 1: FULL-tile row max (both column halves) ----
    const float scale = 0.04419417382415922f;  // 1/sqrt(512)
#pragma unroll
    for (int m = 0; m < 4; ++m)
#pragma unroll
        for (int r = 0; r < 4; ++r) {
            const int rowl = m * 16 + g4 * 4 + r;
            const int row = wr + rowl;
            const int gi = qt * 128 + row;
            const int im = lrepr[row];
            float mx = 0.0f;   // masked entries contribute 0 to the max (reference)
#pragma unroll
            for (int n = 0; n < 4; ++n) {
                const int col = wc + n * 16 + r15;
                const int gj = kt * 128 + col;
                if (im && (gj < gi) && (lrepc[col] != 0))
                    mx = fmaxf(mx, acc[m][n][r] * scale - (float)(gi - gj));
            }
#pragma unroll
            for (int off = 1; off < 16; off <<= 1)
                mx = fmaxf(mx, __shfl_xor(mx, off));
            if (r15 == 0) lst[wid >> 1][rowl][wid & 1][0] = mx;
        }
    __syncthreads();

    // ---- epilogue pass 2: p_t = exp(v - M_t) with TILE-wide M_t; write Pt; sums ----
    u16* ptb = Pt + (size_t)b * PT_BATCH + tri128(qt);
#pragma unroll
    for (int m = 0; m < 4; ++m)
#pragma unroll
        for (int r = 0; r < 4; ++r) {
            const int rowl = m * 16 + g4 * 4 + r;
            const int row = wr + rowl;
            const int gi = qt * 128 + row;
            const int im = lrepr[row];
            const float Mt = fmaxf(lst[wid >> 1][rowl][0][0], lst[wid >> 1][rowl][1][0]);
            float sm = 0.0f;
#pragma unroll
            for (int n = 0; n < 4; ++n) {
                const int col = wc + n * 16 + r15;
                const int gj = kt * 128 + col;
                const bool val = im && (gj < gi) && (lrepc[col] != 0);
                float pt = val ? __expf(acc[m][n][r] * scale - (float)(gi - gj) - Mt) : 0.0f;
                sm += pt;
                if (im) ptb[(size_t)row * nkq + kt * 128 + col] = f2bf(pt);
            }
#pragma unroll
            for (int off = 1; off < 16; off <<= 1)
                sm += __shfl_xor(sm, off);
            if (r15 == 0) lst[wid >> 1][rowl][wid & 1][1] = sm;
        }
    __syncthreads();
    if (tid < 128) {
        const int half = tid >> 6, row64 = tid & 63;
        float Mt = fmaxf(lst[half][row64][0][0], lst[half][row64][1][0]);
        float S = lst[half][row64][0][1] + lst[half][row64][1][1];   // same Mt both halves
        st[(((size_t)b * 8 + kt) << 10) + qt * 128 + tid] = make_float2(Mt, S);
    }
}

// ===== pvsm: merge stats -> P fp32 (pure write) + PV MFMA -> out =====
__global__ __launch_bounds__(256) void pvsm_kernel(const u16* __restrict__ Pt,
                                                   const float2* __restrict__ st,
                                                   const int* __restrict__ rep,
                                                   const u16* __restrict__ Vt,
                                                   float* __restrict__ attn,
                                                   float* __restrict__ out) {
    const int bid = blockIdx.x;
    const int xcd = bid & 7, w = bid >> 3;   // 0..63
    const int b = xcd * 2 + (w & 1);
    const int r_ = w >> 1;                   // 0..31
    const int dt = r_ & 3, qt = 7 - (r_ >> 2);   // LPT; 4 dt of a qt co-resident
    const int nk = (qt + 1) * 128;

    __shared__ u16 lA[128 * 64];
    __shared__ u16 lB[128 * 64];
    __shared__ float lC[128][8];
    __shared__ int lmi[128];

    const int tid = threadIdx.x, lane = tid & 63, wid = tid >> 6;
    const int l8 = lane >> 3, l7 = lane & 7;
    const int cswz = (l7 ^ l8) * 8;
    const int r15 = lane & 15, g4 = lane >> 4;

    if (tid < 128) {
        const int gi = qt * 128 + tid;
        float M = 0.0f, S = 0.0f;
        for (int kt = 0; kt <= qt; ++kt) {
            float2 ms = st[(((size_t)b * 8 + kt) << 10) + gi];
            float Mn = fmaxf(M, ms.x);
            S = S * __expf(M - Mn) + ms.y * __expf(ms.x - Mn);
            M = Mn;
        }
        const float inv = 1.0f / ((S == 0.0f ? 1.0f : S) + 1e-20f);
        for (int kt = 0; kt <= qt; ++kt) {
            float2 ms = st[(((size_t)b * 8 + kt) << 10) + gi];
            lC[tid][kt] = __expf(ms.x - M) * inv;
        }
        lmi[tid] = rep[(size_t)b * S_ + gi];
    }
    __syncthreads();

    const u16* pts = Pt + (size_t)b * PT_BATCH + tri128(qt);
    float* aw = attn + ((size_t)b * S_ + (size_t)qt * 128) * S_;
    const u16* bg = Vt + ((size_t)b * D_ + (size_t)dt * 128) * S_;
    const u16* gb[4];
#pragma unroll
    for (int q2 = 0; q2 < 4; ++q2)
        gb[q2] = bg + (size_t)((wid * 4 + q2) * 8 + l8) * S_ + cswz;

    const int au = tid & 7;
    const int ar0 = (tid >> 3) * 4;

    f32x4 acc[4][4] = {};
    const int wr = (wid >> 1) * 64, wc = (wid & 1) * 64;
    const int cb = g4 * 16;

    for (int kk = 0; kk < nk; kk += 64) {
#pragma unroll
        for (int q2 = 0; q2 < 4; ++q2)
            GLD16(gb[q2] + kk, lB + (wid * 4 + q2) * 512);
#pragma unroll
        for (int rr = 0; rr < 4; ++rr) {
            int row = ar0 + rr;
            float pf[8];
            if (lmi[row]) {   // Pt valid only for unmasked rows (avoids reading poison)
                union { s16x8 v; u16 h[8]; } pt;
                pt.v = *(const s16x8*)(pts + (size_t)row * nk + kk + au * 8);
                const float cc = lC[row][kk >> 7];
#pragma unroll
                for (int e = 0; e < 8; ++e) pf[e] = bf2f(pt.h[e]) * cc;
            } else {
#pragma unroll
                for (int e = 0; e < 8; ++e) pf[e] = 0.0f;
            }
            union { ushort4 h[2]; s16x8 v; } rv;
            rv.h[0] = make_ushort4(f2bf(pf[0]), f2bf(pf[1]), f2bf(pf[2]), f2bf(pf[3]));
            rv.h[1] = make_ushort4(f2bf(pf[4]), f2bf(pf[5]), f2bf(pf[6]), f2bf(pf[7]));
            *(s16x8*)(lA + row * 64 + (au ^ (row & 7)) * 8) = rv.v;
            if (dt == 0) {   // final P fp32: pure write, nobody reads attn -> race-free
                float* dst = aw + (size_t)row * S_ + kk + au * 8;
                *(float4*)dst = make_float4(pf[0], pf[1], pf[2], pf[3]);
                *(float4*)(dst + 4) = make_float4(pf[4], pf[5], pf[6], pf[7]);
            }
        }
        __syncthreads();
#pragma unroll
        for (int ks = 0; ks < 2; ++ks) {
            s16x8 af[4], bf4[4];
#pragma unroll
            for (int m = 0; m < 4; ++m) af[m] = frag_swz(lA, wr + m * 16 + r15, ks * 64 + cb);
#pragma unroll
            for (int n = 0; n < 4; ++n) bf4[n] = frag_swz(lB, wc + n * 16 + r15, ks * 64 + cb);
#pragma unroll
            for (int m = 0; m < 4; ++m)
#pragma unroll
                for (int n = 0; n < 4; ++n)
                    acc[m][n] = __builtin_amdgcn_mfma_f32_16x16x32_bf16(af[m], bf4[n], acc[m][n], 0, 0, 0);
        }
        __syncthreads();
    }

    if (dt == 1) {   // zero the causal tail of the attn stripe
        const int tail = S_ - nk;
        for (int t2 = tid * 4; t2 < 128 * tail; t2 += 1024) {
            int row = t2 / tail, c2 = t2 - row * tail;
            *(float4*)(aw + (size_t)row * S_ + nk + c2) = make_float4(0.f, 0.f, 0.f, 0.f);
        }
    }

    size_t base = ((size_t)b * S_ + (size_t)qt * 128) * D_ + (size_t)dt * 128;
    const int rr2 = (lane >> 4) * 4;
#pragma unroll
    for (int m = 0; m < 4; ++m)
#pragma unroll
        for (int n = 0; n < 4; ++n)
#pragma unroll
            for (int r = 0; r < 4; ++r)
                out[base + (size_t)(wr + m * 16 + rr2 + r) * D_ + wc + n * 16 + r15] =
                    acc[m][n][r];
}

// ======================= legacy fallback path (no ws) =======================

union Frag { s16x8 v; uint2 u[2]; };

__device__ __forceinline__ s16x8 load_frag(const u16* lds, int row, int kq) {
    Frag f;
    const u16* p = lds + row * PITCH + kq;
    f.u[0] = *(const uint2*)p;
    f.u[1] = *(const uint2*)(p + 4);
    return f.v;
}

__device__ __forceinline__ void stage_granule(u16* lds, const float* src, int ldsrc, int g) {
    int row = g >> 2;
    int c8 = (g & 3) * 8;
    const float4* s = (const float4*)(src + (size_t)row * ldsrc + c8);
    float4 x0 = s[0], x1 = s[1];
    *(ushort4*)(lds + row * PITCH + c8) =
        make_ushort4(f2bf(x0.x), f2bf(x0.y), f2bf(x0.z), f2bf(x0.w));
    *(ushort4*)(lds + row * PITCH + c8 + 4) =
        make_ushort4(f2bf(x1.x), f2bf(x1.y), f2bf(x1.z), f2bf(x1.w));
}

__global__ __launch_bounds__(256) void qk_kernel(const float* __restrict__ q,
                                                 const float* __restrict__ k,
                                                 float* __restrict__ attn) {
    const int kt = blockIdx.x, qt = blockIdx.y, b = blockIdx.z;
    if (kt > qt) return;
    __shared__ u16 lA[TILE * PITCH];
    __shared__ u16 lB[TILE * PITCH];
    const int tid = threadIdx.x;
    const int lane = tid & 63;
    const int wid = tid >> 6;
    const int wr = (wid >> 1) * 64, wc = (wid & 1) * 64;
    const int r15 = lane & 15, kq = (lane >> 4) * 8;
    const float* qb = q + ((size_t)b * S_ + (size_t)qt * TILE) * D_;
    const float* kb = k + ((size_t)b * S_ + (size_t)kt * TILE) * D_;
    f32x4 acc[4][4] = {};
    for (int kk = 0; kk < D_; kk += BK) {
        __syncthreads();
        stage_granule(lA, qb + kk, D_, tid);
        stage_granule(lA, qb + kk, D_, tid + 256);
        stage_granule(lB, kb + kk, D_, tid);
        stage_granule(lB, kb + kk, D_, tid + 256);
        __syncthreads();
        s16x8 af[4], bf[4];
#pragma unroll
        for (int m = 0; m < 4; ++m) af[m] = load_frag(lA, wr + m * 16 + r15, kq);
#pragma unroll
        for (int n = 0; n < 4; ++n) bf[n] = load_frag(lB, wc + n * 16 + r15, kq);
#pragma unroll
        for (int m = 0; m < 4; ++m)
#pragma unroll
            for (int n = 0; n < 4; ++n)
                acc[m][n] = __builtin_amdgcn_mfma_f32_16x16x32_bf16(af[m], bf[n], acc[m][n], 0, 0, 0);
    }
    const float scale = 0.04419417382415922f;
    size_t base = ((size_t)b * S_ + (size_t)qt * TILE) * S_ + (size_t)kt * TILE;
    const int rr = (lane >> 4) * 4;
#pragma unroll
    for (int m = 0; m < 4; ++m)
#pragma unroll
        for (int n = 0; n < 4; ++n)
#pragma unroll
            for (int r = 0; r < 4; ++r)
                attn[base + (size_t)(wr + m * 16 + rr + r) * S_ + wc + n * 16 + r15] =
                    acc[m][n][r] * scale;
}

__global__ __launch_bounds__(256) void sm_kernel(const int* __restrict__ rep_mask,
                                                 float* __restrict__ attn) {
    const int i = blockIdx.x, b = blockIdx.y;
    const int tid = threadIdx.x;
    const int lane = tid & 63, wid = tid >> 6;
    float* row = attn + ((size_t)b * S_ + i) * S_;
    const int* rm = rep_mask + (size_t)b * S_;
    __shared__ float red[8];
    const int mi = rm[i];
    const int j0 = tid * 4;
    int4 m4 = ((const int4*)rm)[tid];
    float4 lv = make_float4(0.f, 0.f, 0.f, 0.f);
    if (mi != 0 && j0 < i) lv = *(const float4*)(row + j0);
    const int mv[4] = {m4.x, m4.y, m4.z, m4.w};
    const float lf[4] = {lv.x, lv.y, lv.z, lv.w};
    float vec[4];
    bool val[4];
    float mymax = 0.0f;
#pragma unroll
    for (int e = 0; e < 4; ++e) {
        int j = j0 + e;
        val[e] = (mi != 0) && (j < i) && (mv[e] != 0);
        vec[e] = lf[e] - (float)(i - j);
        if (val[e]) mymax = fmaxf(mymax, vec[e]);
    }
#pragma unroll
    for (int off = 32; off > 0; off >>= 1) mymax = fmaxf(mymax, __shfl_down(mymax, off));
    if (lane == 0) red[wid] = mymax;
    __syncthreads();
    const float m = fmaxf(fmaxf(red[0], red[1]), fmaxf(red[2], red[3]));
    float ex[4];
    float mysum = 0.0f;
#pragma unroll
    for (int e = 0; e < 4; ++e) {
        ex[e] = val[e] ? expf(vec[e] - m) : 0.0f;
        mysum += ex[e];
    }
#pragma unroll
    for (int off = 32; off > 0; off >>= 1) mysum += __shfl_down(mysum, off);
    if (lane == 0) red[4 + wid] = mysum;
    __syncthreads();
    const float ssum = red[4] + red[5] + red[6] + red[7];
    const float denom = ssum + (ssum == 0.0f ? 1.0f : 0.0f) + 1e-20f;
    const float inv = 1.0f / denom;
    *(float4*)(row + j0) = make_float4(ex[0] * inv, ex[1] * inv, ex[2] * inv, ex[3] * inv);
}

__global__ __launch_bounds__(256) void pv_kernel(const float* __restrict__ attn,
                                                 const float* __restrict__ v,
                                                 float* __restrict__ out) {
    const int dt = blockIdx.x, qt = blockIdx.y, b = blockIdx.z;
    __shared__ u16 lP[TILE * PITCH];
    __shared__ u16 lV[TILE * PITCH];
    const int tid = threadIdx.x;
    const int lane = tid & 63;
    const int wid = tid >> 6;
    const int wr = (wid >> 1) * 64, wc = (wid & 1) * 64;
    const int r15 = lane & 15, kq = (lane >> 4) * 8;
    const float* pb = attn + ((size_t)b * S_ + (size_t)qt * TILE) * S_;
    const float* vb = v + (size_t)b * S_ * D_ + (size_t)dt * TILE;
    const int vd0 = (tid & 31) * 4;
    const int vj0 = (tid >> 5) * 4;
    f32x4 acc[4][4] = {};
    const int nk = (qt + 1) * TILE;
    for (int kk = 0; kk < nk; kk += BK) {
        __syncthreads();
        stage_granule(lP, pb + kk, S_, tid);
        stage_granule(lP, pb + kk, S_, tid + 256);
        {
            const float* vs = vb + (size_t)(kk + vj0) * D_ + vd0;
            float4 r0 = *(const float4*)vs;
            float4 r1 = *(const float4*)(vs + D_);
            float4 r2 = *(const float4*)(vs + 2 * D_);
            float4 r3 = *(const float4*)(vs + 3 * D_);
            *(ushort4*)(lV + (vd0 + 0) * PITCH + vj0) = make_ushort4(f2bf(r0.x), f2bf(r1.x), f2bf(r2.x), f2bf(r3.x));
            *(ushort4*)(lV + (vd0 + 1) * PITCH + vj0) = make_ushort4(f2bf(r0.y), f2bf(r1.y), f2bf(r2.y), f2bf(r3.y));
            *(ushort4*)(lV + (vd0 + 2) * PITCH + vj0) = make_ushort4(f2bf(r0.z), f2bf(r1.z), f2bf(r2.z), f2bf(r3.z));
            *(ushort4*)(lV + (vd0 + 3) * PITCH + vj0) = make_ushort4(f2bf(r0.w), f2bf(r1.w), f2bf(r2.w), f2bf(r3.w));
        }
        __syncthreads();
        s16x8 af[4], bf[4];
#pragma unroll
        for (int m = 0; m < 4; ++m) af[m] = load_frag(lP, wr + m * 16 + r15, kq);
#pragma unroll
        for (int n = 0; n < 4; ++n) bf[n] = load_frag(lV, wc + n * 16 + r15, kq);
#pragma unroll
        for (int m = 0; m < 4; ++m)
#pragma unroll
            for (int n = 0; n < 4; ++n)
                acc[m][n] = __builtin_amdgcn_mfma_f32_16x16x32_bf16(af[m], bf[n], acc[m][n], 0, 0, 0);
    }
    size_t base = ((size_t)b * S_ + (size_t)qt * TILE) * D_ + (size_t)dt * TILE;
    const int rr = (lane >> 4) * 4;
#pragma unroll
    for (int m = 0; m < 4; ++m)
#pragma unroll
        for (int n = 0; n < 4; ++n)
#pragma unroll
            for (int r = 0; r < 4; ++r)
                out[base + (size_t)(wr + m * 16 + rr + r) * D_ + wc + n * 16 + r15] =
                    acc[m][n][r];
}

extern "C" void kernel_launch(void* const* d_in, const int* in_sizes, int n_in,
                              void* d_out, int out_size, void* d_ws, size_t ws_size,
                              hipStream_t stream) {
    const float* q = (const float*)d_in[0];
    const float* k = (const float*)d_in[1];
    const float* v = (const float*)d_in[2];
    const int* rep = (const int*)d_in[3];
    float* out = (float*)d_out;
    float* attn = out + (size_t)B_ * S_ * D_;   // second output region [B,S,S]

    const size_t nqk = (size_t)B_ * S_ * D_;        // 8.4M
    const size_t npt = (size_t)B_ * PT_BATCH;       // 9.4M
    const size_t nst = (size_t)B_ * 8 * S_;         // stats float2
    const size_t need = 2 * nqk * sizeof(u16) + npt * sizeof(u16) + nst * sizeof(float2);  // 53.5 MB
    if (ws_size >= need) {
        u16* Kb = (u16*)d_ws;
        u16* Vt = Kb + nqk;
        u16* Pt = Vt + nqk;
        float2* st = (float2*)(Pt + npt);
        prep2_kernel<<<6144, 256, 0, stream>>>(k, v, Kb, Vt);
        qk3_kernel<<<8 * 72, 256, 0, stream>>>(q, Kb, rep, Pt, st);
        pvsm_kernel<<<8 * 64, 256, 0, stream>>>(Pt, st, rep, Vt, attn, out);
    } else {
        qk_kernel<<<dim3(S_ / TILE, S_ / TILE, B_), 256, 0, stream>>>(q, k, attn);
        sm_kernel<<<dim3(S_, B_), 256, 0, stream>>>(rep, attn);
        pv_kernel<<<dim3(D_ / TILE, S_ / TILE, B_), 256, 0, stream>>>(attn, v, out);
    }
}